// Round 3
// baseline (212.977 us; speedup 1.0000x reference)
//
#include <hip/hip_runtime.h>

#define POOLSZ 7
#define IMG_H  28
#define IMG_W  28
#define IMG_C  512
#define C4     128            // float4 groups per pixel (512/4)
#define TOT_ROIS 2048         // 16 * 128 from the reshape

typedef float f4 __attribute__((ext_vector_type(4)));

// v4: no LDS, no barrier, no staging. Image (1.6 MB) is L2-resident;
// read the 4 bilinear taps directly from L2 as coalesced 1 KB wave-loads.
// 2048 blocks x 256 threads, 8 waves/SIMD, pure streaming.
__global__ __launch_bounds__(256, 8)
void roi_crop_resize_v4(const float* __restrict__ img,
                        const float* __restrict__ rois,
                        float* __restrict__ out) {
    int n   = blockIdx.x;            // ROI id 0..2047
    int tid = threadIdx.x;

    // boxes: x1 = col3, y1 = col4 of flattened (N,5) rois; both in [0,1)
    float x1 = rois[n * 5 + 3];
    float y1 = rois[n * 5 + 4];
    // replicate reference arithmetic order exactly
    float x2 = x1 + 4.0f / 28.0f;
    float y2 = y1 + 4.0f / 28.0f;
    const float Hm1 = 27.0f, Wm1 = 27.0f;
    float dy  = (y2 - y1) * Hm1 / 6.0f;   // ((y2-y1)*27)/6, same assoc as ref
    float dx  = (x2 - x1) * Wm1 / 6.0f;
    float ys0 = y1 * Hm1;
    float xs0 = x1 * Wm1;

    const f4* img4 = (const f4*)img;      // only img[0] is used
    f4* out4 = (f4*)out + n * 49 * C4;

    // 49 positions x 128 f4; i>>7 (= p) is wave-uniform, c = lane + 64*(wave&1)
    // -> sample math shared across the wave, taps + store fully coalesced.
    for (int i = tid; i < 49 * C4; i += 256) {
        int c = i & (C4 - 1);
        int p = i >> 7;                   // 0..48
        int py = p / POOLSZ, px = p % POOLSZ;

        float ys = ys0 + (float)py * dy;
        float xs = xs0 + (float)px * dx;
        float y0f = floorf(ys), x0f = floorf(xs);
        float ly = ys - y0f, lx = xs - x0f;
        int y0  = (int)fminf(fmaxf(y0f,       0.f), Hm1);
        int y1i = (int)fminf(fmaxf(y0f + 1.f, 0.f), Hm1);
        int x0  = (int)fminf(fmaxf(x0f,       0.f), Wm1);
        int x1i = (int)fminf(fmaxf(x0f + 1.f, 0.f), Wm1);
        float m = ((ys >= 0.f) & (ys <= Hm1) & (xs >= 0.f) & (xs <= Wm1)) ? 1.f : 0.f;

        // 4 taps straight from L2 (img is 1.6 MB, fully cached)
        f4 tl = img4[(y0  * IMG_W + x0 ) * C4 + c];
        f4 tr = img4[(y0  * IMG_W + x1i) * C4 + c];
        f4 bl = img4[(y1i * IMG_W + x0 ) * C4 + c];
        f4 br = img4[(y1i * IMG_W + x1i) * C4 + c];

        float omly = 1.f - ly;
        f4 v = ((tl + (tr - tl) * lx) * omly + (bl + (br - bl) * lx) * ly) * m;

        out4[p * C4 + c] = v;             // plain store, 1 KB/wave contiguous
    }
}

extern "C" void kernel_launch(void* const* d_in, const int* in_sizes, int n_in,
                              void* d_out, int out_size, void* d_ws, size_t ws_size,
                              hipStream_t stream) {
    const float* img  = (const float*)d_in[0];
    const float* rois = (const float*)d_in[1];
    float* out = (float*)d_out;

    roi_crop_resize_v4<<<TOT_ROIS, 256, 0, stream>>>(img, rois, out);
}